// Round 1
// baseline (1610.091 us; speedup 1.0000x reference)
//
#include <hip/hip_runtime.h>

// Block_21380347200224: LN1 -> 3D spectral filter (9x11x9, rfft last axis) -> LN2 ->
// low-rank MLP (900->450->1800 gelu ->450->900) -> +x residual.
// B=64, N=891, C=900, tokens M=57024.
//
// Pipeline:
//  k_cvt x4 + k_bias1 : weights -> bf16 (K-padded, gamma2 folded into u1)
//  k_ln1_dfft  : LN1 + d-axis rfft (9->5)   [block = (b,h,w), owns 9 tokens]
//  k_wfft<0>   : 11-pt DFT over w           (in-place, complex planes fre/fim)
//  k_hfilter   : 9-pt DFT over h * weight * 9-pt iDFT   (in-place)
//  k_wfft<1>   : 11-pt iDFT over w          (in-place)
//  k_difft_ln2 : d-axis irfft (5->9) + LN2 -> ynorm bf16 (in d_out, K-pad 928)
//  k_gemm<0..3>: bf16 MFMA GEMMs (m97-style 128x128 tile, global_load_lds w=16)
//                epilogues: +bias / gelu / plain / +v2_b + x residual -> out fp32
//
// ws layout (~292 MB):  [0,228.1M) fre+fim, reused as t2 (57024x1824 bf16)
//                       [228.1M, 286.5M) t3 ; then bf16 weights + bias1r
// d_out reused as scratch: ynorm [0,105.8M), t1 [105.8M,164.2M) — dead before final GEMM writes out.

typedef unsigned short u16;
typedef __bf16 bf16x8 __attribute__((ext_vector_type(8)));
typedef float f32x4 __attribute__((ext_vector_type(4)));

#define LN_EPS 1e-5f

// ---------------- twiddle tables (folded to immediates after unroll) ----------------
constexpr float KC9[9] = {
  1.0f, 0.766044443118978f, 0.17364817766693041f, -0.4999999999999998f,
  -0.9396926207859083f, -0.9396926207859084f, -0.5000000000000004f,
  0.17364817766692997f, 0.7660444431189778f };
constexpr float KS9[9] = {
  0.0f, 0.6427876096865393f, 0.984807753012208f, 0.8660254037844387f,
  0.3420201433256689f, -0.34202014332566866f, -0.8660254037844385f,
  -0.9848077530122081f, -0.6427876096865396f };
constexpr float KC11[11] = {
  1.0f, 0.8412535328311812f, 0.41541501300188644f, -0.14231483827328512f,
  -0.654860733945285f, -0.9594929736144974f, -0.9594929736144974f,
  -0.6548607339452852f, -0.14231483827328543f, 0.4154150130018863f,
  0.8412535328311811f };
constexpr float KS11[11] = {
  0.0f, 0.5406408174555976f, 0.9096319953545183f, 0.9898214418809327f,
  0.7557495743542583f, 0.2817325568414297f, -0.2817325568414296f,
  -0.7557495743542582f, -0.9898214418809327f, -0.9096319953545184f,
  -0.5406408174555979f };

__device__ __forceinline__ u16 f2bf(float f) {           // RNE float->bf16 (finite vals)
  unsigned int u = __float_as_uint(f);
  return (u16)((u + 0x7fffu + ((u >> 16) & 1u)) >> 16);
}
__device__ __forceinline__ float gelu_f(float v) {       // exact gelu
  return 0.5f * v * (1.f + erff(v * 0.70710678118654752440f));
}

// ---------------- weight conversion ----------------
__global__ __launch_bounds__(256) void k_cvt(const float* __restrict__ s, u16* __restrict__ d,
                                             int rows, int sc, int dc,
                                             const float* __restrict__ gamma) {
  int i = blockIdx.x * 256 + threadIdx.x;
  if (i >= rows * dc) return;
  int r = i / dc, c = i % dc;
  u16 o = 0;
  if (c < sc) {
    float v = s[(size_t)r * sc + c];
    if (gamma) v *= gamma[c];
    o = f2bf(v);
  }
  d[i] = o;
}

__global__ __launch_bounds__(256) void k_bias1(const float* __restrict__ u1w,
                                               const float* __restrict__ b2,
                                               float* __restrict__ out) {
  int r = blockIdx.x * 256 + threadIdx.x;
  if (r < 450) {
    float s = 0.f;
    for (int c = 0; c < 900; c++) s += u1w[r * 900 + c] * b2[c];
    out[r] = s;  // beta2 folded through u1: t1 += u1w . beta2
  }
}

// ---------------- stage 1: LN1 + d-axis rfft (9 -> 5) ----------------
__global__ __launch_bounds__(256) void k_ln1_dfft(const float* __restrict__ x,
                                                  const float* __restrict__ g1,
                                                  const float* __restrict__ b1,
                                                  float* __restrict__ fre,
                                                  float* __restrict__ fim) {
  __shared__ float red1[9][256], red2[9][256];
  __shared__ float smu[9], srs[9];
  int blk = blockIdx.x;                 // b*99 + h*11 + w  -> token base blk*9
  int t = threadIdx.x;
  const float* xb = x + (size_t)blk * 8100;   // 9 tokens * 900

  float v[4][9], s1[9], s2[9];
#pragma unroll
  for (int d = 0; d < 9; d++) { s1[d] = 0.f; s2[d] = 0.f; }
#pragma unroll
  for (int i = 0; i < 4; i++) {
    int c = t + i * 256;
    bool ok = c < 900;
#pragma unroll
    for (int d = 0; d < 9; d++) {
      float a = ok ? xb[d * 900 + c] : 0.f;
      v[i][d] = a; s1[d] += a; s2[d] += a * a;
    }
  }
#pragma unroll
  for (int d = 0; d < 9; d++) { red1[d][t] = s1[d]; red2[d][t] = s2[d]; }
  __syncthreads();
  int w = t >> 6, l = t & 63;
  for (int d = w; d < 9; d += 4) {
    float p1 = red1[d][l] + red1[d][l + 64] + red1[d][l + 128] + red1[d][l + 192];
    float p2 = red2[d][l] + red2[d][l + 64] + red2[d][l + 128] + red2[d][l + 192];
#pragma unroll
    for (int off = 32; off > 0; off >>= 1) { p1 += __shfl_down(p1, off, 64); p2 += __shfl_down(p2, off, 64); }
    if (l == 0) {
      float m = p1 * (1.f / 900.f);
      float var = p2 * (1.f / 900.f) - m * m;
      smu[d] = m; srs[d] = rsqrtf(var + LN_EPS);
    }
  }
  __syncthreads();
  float mu[9], rs[9];
#pragma unroll
  for (int d = 0; d < 9; d++) { mu[d] = smu[d]; rs[d] = srs[d]; }

  size_t ob = (size_t)blk * 4500;       // (blk*5 + kd)*900
#pragma unroll
  for (int i = 0; i < 4; i++) {
    int c = t + i * 256;
    if (c < 900) {
      float g = g1[c], be = b1[c];
      float y[9];
#pragma unroll
      for (int d = 0; d < 9; d++) y[d] = (v[i][d] - mu[d]) * rs[d] * g + be;
#pragma unroll
      for (int kd = 0; kd < 5; kd++) {
        float re = 0.f, im = 0.f;
#pragma unroll
        for (int d = 0; d < 9; d++) { int j = (kd * d) % 9; re += y[d] * KC9[j]; im -= y[d] * KS9[j]; }
        fre[ob + (size_t)kd * 900 + c] = re;
        fim[ob + (size_t)kd * 900 + c] = im;
      }
    }
  }
}

// ---------------- stage 2/4: 11-pt DFT over w (INV=0 fwd, INV=1 inverse) ----------------
template <int INV>
__global__ __launch_bounds__(256) void k_wfft(float* __restrict__ fre, float* __restrict__ fim) {
  int blk = blockIdx.x;                 // (b*9+h)*5 + kd
  int kd = blk % 5, bh = blk / 5;
  size_t base = (size_t)bh * 49500 + (size_t)kd * 900;   // ((bh*11 + w)*5 + kd)*900
  int t = threadIdx.x;
  for (int c = t; c < 900; c += 256) {
    float xr[11], xi[11];
#pragma unroll
    for (int ww = 0; ww < 11; ww++) {
      size_t p = base + (size_t)ww * 4500 + c;
      xr[ww] = fre[p]; xi[ww] = fim[p];
    }
#pragma unroll
    for (int k = 0; k < 11; k++) {
      float yr = 0.f, yi = 0.f;
#pragma unroll
      for (int ww = 0; ww < 11; ww++) {
        int j = (k * ww) % 11;
        float cc = KC11[j], ss = KS11[j];
        if (INV) { yr += xr[ww] * cc - xi[ww] * ss; yi += xi[ww] * cc + xr[ww] * ss; }
        else     { yr += xr[ww] * cc + xi[ww] * ss; yi += xi[ww] * cc - xr[ww] * ss; }
      }
      size_t p = base + (size_t)k * 4500 + c;
      fre[p] = yr; fim[p] = yi;
    }
  }
}

// ---------------- stage 3: 9-pt DFT over h, * weight, 9-pt iDFT ----------------
__global__ __launch_bounds__(256) void k_hfilter(float* __restrict__ fre, float* __restrict__ fim,
                                                 const float* __restrict__ cw) {
  int blk = blockIdx.x;                 // b*55 + (kw*5 + kd)
  int b = blk / 55, r = blk % 55;
  size_t base = ((size_t)b * 495 + r) * 900;
  size_t wb = (size_t)r * 900;
  int t = threadIdx.x;
  for (int c = t; c < 900; c += 256) {
    float xr[9], xi[9];
#pragma unroll
    for (int h = 0; h < 9; h++) { size_t p = base + (size_t)h * 49500 + c; xr[h] = fre[p]; xi[h] = fim[p]; }
    float zr[9], zi[9];
#pragma unroll
    for (int k = 0; k < 9; k++) {
      float yr = 0.f, yi = 0.f;
#pragma unroll
      for (int h = 0; h < 9; h++) {
        int j = (k * h) % 9; float cc = KC9[j], ss = KS9[j];
        yr += xr[h] * cc + xi[h] * ss;
        yi += xi[h] * cc - xr[h] * ss;
      }
      size_t widx = (wb + (size_t)k * 49500 + c) * 2;   // cw (kh,kw,kd,c,2)
      float wr = cw[widx], wim = cw[widx + 1];
      zr[k] = yr * wr - yi * wim;
      zi[k] = yr * wim + yi * wr;
    }
#pragma unroll
    for (int h = 0; h < 9; h++) {
      float orr = 0.f, oi = 0.f;
#pragma unroll
      for (int k = 0; k < 9; k++) {
        int j = (k * h) % 9; float cc = KC9[j], ss = KS9[j];
        orr += zr[k] * cc - zi[k] * ss;
        oi  += zi[k] * cc + zr[k] * ss;
      }
      size_t p = base + (size_t)h * 49500 + c;
      fre[p] = orr; fim[p] = oi;
    }
  }
}

// ---------------- stage 5: d-axis irfft (5 -> 9) + LN2 -> ynorm bf16 (K-pad 928) ----------------
__global__ __launch_bounds__(256) void k_difft_ln2(const float* __restrict__ fre,
                                                   const float* __restrict__ fim,
                                                   u16* __restrict__ yn) {
  __shared__ float red1[9][256], red2[9][256];
  __shared__ float smu[9], srs[9];
  int blk = blockIdx.x;
  int t = threadIdx.x;
  size_t ib = (size_t)blk * 4500;

  float v[4][9], s1[9], s2[9];
#pragma unroll
  for (int d = 0; d < 9; d++) { s1[d] = 0.f; s2[d] = 0.f; }
#pragma unroll
  for (int i = 0; i < 4; i++) {
    int c = t + i * 256;
    bool ok = c < 900;
    int cc = ok ? c : 0;
    float Xr[5], Xi[5];
#pragma unroll
    for (int k = 0; k < 5; k++) { size_t p = ib + (size_t)k * 900 + cc; Xr[k] = fre[p]; Xi[k] = fim[p]; }
#pragma unroll
    for (int d = 0; d < 9; d++) {
      float acc = Xr[0];
#pragma unroll
      for (int k = 1; k < 5; k++) { int j = (k * d) % 9; acc += 2.f * (Xr[k] * KC9[j] - Xi[k] * KS9[j]); }
      acc *= (1.f / 891.f);             // ortho norm both directions (1/sqrt(891))^2
      if (!ok) acc = 0.f;
      v[i][d] = acc; s1[d] += acc; s2[d] += acc * acc;
    }
  }
#pragma unroll
  for (int d = 0; d < 9; d++) { red1[d][t] = s1[d]; red2[d][t] = s2[d]; }
  __syncthreads();
  int w = t >> 6, l = t & 63;
  for (int d = w; d < 9; d += 4) {
    float p1 = red1[d][l] + red1[d][l + 64] + red1[d][l + 128] + red1[d][l + 192];
    float p2 = red2[d][l] + red2[d][l + 64] + red2[d][l + 128] + red2[d][l + 192];
#pragma unroll
    for (int off = 32; off > 0; off >>= 1) { p1 += __shfl_down(p1, off, 64); p2 += __shfl_down(p2, off, 64); }
    if (l == 0) {
      float m = p1 * (1.f / 900.f);
      float var = p2 * (1.f / 900.f) - m * m;
      smu[d] = m; srs[d] = rsqrtf(var + LN_EPS);
    }
  }
  __syncthreads();
  float mu[9], rs[9];
#pragma unroll
  for (int d = 0; d < 9; d++) { mu[d] = smu[d]; rs[d] = srs[d]; }

  size_t tok0 = (size_t)blk * 9;
#pragma unroll
  for (int i = 0; i < 4; i++) {
    int c = t + i * 256;
    if (c < 900) {
#pragma unroll
      for (int d = 0; d < 9; d++)
        yn[(tok0 + d) * 928 + c] = f2bf((v[i][d] - mu[d]) * rs[d]);  // gamma2/beta2 folded into GEMM1
    }
  }
  if (t < 28) {
#pragma unroll
    for (int d = 0; d < 9; d++) yn[(tok0 + d) * 928 + 900 + t] = 0;  // K padding
  }
}

// ---------------- bf16 MFMA GEMM, C = A(MxK) . B(NxK)^T, m97-style ----------------
typedef __attribute__((address_space(1))) void gvoid;
typedef __attribute__((address_space(3))) void svoid;

__device__ __forceinline__ void stage16(const u16* g, u16* lbase, int lane) {
#if __has_builtin(__builtin_amdgcn_global_load_lds)
  // HW scatters lane i at lbase + i*16B; our layout is exactly chunk-contiguous.
  __builtin_amdgcn_global_load_lds((gvoid*)(void*)g, (svoid*)lbase, 16, 0, 0);
#else
  *(uint4*)(lbase + lane * 8) = *(const uint4*)g;
#endif
}

// EPI: 0 = bf16 store + bias (G1)   1 = bf16 store gelu(.+bias) (G2)
//      2 = bf16 store plain (G3)    3 = fp32 out = . + bias + x (G4)
template <int EPI>
__global__ __launch_bounds__(256, 2) void k_gemm(
    const u16* __restrict__ A, const u16* __restrict__ B,
    int M, int N, int Kt, int ldk, int NT,
    u16* __restrict__ Ob, int ldo, int Nstore,
    const float* __restrict__ bias,
    const float* __restrict__ Xres, float* __restrict__ Of) {
  __shared__ u16 As[128 * 32];
  __shared__ u16 Bs[128 * 32];
  int t = threadIdx.x, w = t >> 6, l = t & 63;
  int mt = blockIdx.x / NT, nt = blockIdx.x % NT;
  int m0 = mt * 128, n0 = nt * 128;
  int arow = (w << 4) + (l >> 2);       // staging row within 64-row call
  int koff = (l & 3) * 8;               // bf16 elements
  int wm = (w >> 1) << 6, wn = (w & 1) << 6;
  int fr = l & 15, fq = l >> 4;

  f32x4 acc[4][4];
  f32x4 zero = {0.f, 0.f, 0.f, 0.f};
#pragma unroll
  for (int i = 0; i < 4; i++)
#pragma unroll
    for (int j = 0; j < 4; j++) acc[i][j] = zero;

  for (int kt = 0; kt < Kt; ++kt) {
    int k0 = kt * 32;
#pragma unroll
    for (int j = 0; j < 2; j++) {
      int r = (j << 6) + arow;
      int gm = m0 + r; gm = gm < M ? gm : M - 1;          // clamp; results discarded on store
      stage16(A + (size_t)gm * ldk + (k0 + koff), &As[((j << 6) + (w << 4)) * 32], l);
      int gn = n0 + r; gn = gn < N ? gn : N - 1;
      stage16(B + (size_t)gn * ldk + (k0 + koff), &Bs[((j << 6) + (w << 4)) * 32], l);
    }
    __syncthreads();                    // drains vmcnt (global_load_lds) too
    bf16x8 af[4], bfr[4];
#pragma unroll
    for (int i = 0; i < 4; i++) af[i] = *(const bf16x8*)&As[(wm + (i << 4) + fr) * 32 + fq * 8];
#pragma unroll
    for (int i = 0; i < 4; i++) bfr[i] = *(const bf16x8*)&Bs[(wn + (i << 4) + fr) * 32 + fq * 8];
#pragma unroll
    for (int i = 0; i < 4; i++)
#pragma unroll
      for (int j = 0; j < 4; j++)
        acc[i][j] = __builtin_amdgcn_mfma_f32_16x16x32_bf16(af[i], bfr[j], acc[i][j], 0, 0, 0);
    __syncthreads();
  }

#pragma unroll
  for (int j = 0; j < 4; j++) {
    int gn = n0 + wn + (j << 4) + fr;   // C/D: col = lane&15
    float bv = 0.f;
    if (EPI != 2) bv = (gn < Nstore) ? bias[gn] : 0.f;
#pragma unroll
    for (int i = 0; i < 4; i++) {
#pragma unroll
      for (int r = 0; r < 4; r++) {
        int gm = m0 + wm + (i << 4) + (fq << 2) + r;   // row = (lane>>4)*4 + reg
        if (gm < M) {
          float val = acc[i][j][r] + bv;
          if (EPI == 1) val = gelu_f(val);
          if (EPI == 3) {
            if (gn < Nstore) Of[(size_t)gm * Nstore + gn] = val + Xres[(size_t)gm * Nstore + gn];
          } else {
            if (gn < ldo) Ob[(size_t)gm * ldo + gn] = (gn < Nstore) ? f2bf(val) : (u16)0;
          }
        }
      }
    }
  }
}

// ---------------- launch ----------------
extern "C" void kernel_launch(void* const* d_in, const int* in_sizes, int n_in,
                              void* d_out, int out_size, void* d_ws, size_t ws_size,
                              hipStream_t stream) {
  const float* x   = (const float*)d_in[0];
  const float* cw  = (const float*)d_in[1];
  const float* g1  = (const float*)d_in[2];
  const float* b1  = (const float*)d_in[3];
  const float* g2  = (const float*)d_in[4];
  const float* b2  = (const float*)d_in[5];
  const float* u1w = (const float*)d_in[6];
  const float* v1w = (const float*)d_in[7];
  const float* v1b = (const float*)d_in[8];
  const float* u2w = (const float*)d_in[9];
  const float* v2w = (const float*)d_in[10];
  const float* v2b = (const float*)d_in[11];

  char* ws = (char*)d_ws;
  float* fre = (float*)ws;                                   // 114,048,000 B
  float* fim = (float*)(ws + 114048000);                     // 114,048,000 B
  u16*   t2  = (u16*)ws;                                     // reuse: 57024*1824*2 = 208,023,552 B
  u16*   t3  = (u16*)(ws + 228096000);                       // 58,392,576 B
  u16*   u1g = (u16*)(ws + 286488576);                       // 450*928*2
  u16*   v1c = (u16*)(ws + 287323776);                       // 1800*512*2
  u16*   u2c = (u16*)(ws + 289166976);                       // 450*1824*2
  u16*   v2c = (u16*)(ws + 290808576);                       // 900*512*2
  float* b1r = (float*)(ws + 291730176);                     // 450*4

  u16*   yn  = (u16*)d_out;                                  // 57024*928*2 = 105,836,544 B
  u16*   t1  = (u16*)((char*)d_out + 105836544);             // 57024*512*2 = 58,392,576 B
  float* outF = (float*)d_out;

  // weight prep (tiny)
  k_cvt<<<1632, 256, 0, stream>>>(u1w, u1g, 450, 900, 928, g2);
  k_cvt<<<3600, 256, 0, stream>>>(v1w, v1c, 1800, 450, 512, nullptr);
  k_cvt<<<3207, 256, 0, stream>>>(u2w, u2c, 450, 1800, 1824, nullptr);
  k_cvt<<<1800, 256, 0, stream>>>(v2w, v2c, 900, 450, 512, nullptr);
  k_bias1<<<2, 256, 0, stream>>>(u1w, b2, b1r);

  // spectral filter
  k_ln1_dfft<<<6336, 256, 0, stream>>>(x, g1, b1, fre, fim);
  k_wfft<0><<<2880, 256, 0, stream>>>(fre, fim);
  k_hfilter<<<3520, 256, 0, stream>>>(fre, fim, cw);
  k_wfft<1><<<2880, 256, 0, stream>>>(fre, fim);
  k_difft_ln2<<<6336, 256, 0, stream>>>(fre, fim, yn);

  // MLP GEMMs: M=57024 (446 tiles of 128)
  k_gemm<0><<<446 * 4,  256, 0, stream>>>(yn, u1g, 57024, 450,  29, 928,  4,  t1, 512, 450, b1r, nullptr, nullptr);
  k_gemm<1><<<446 * 15, 256, 0, stream>>>(t1, v1c, 57024, 1800, 16, 512,  15, t2, 1824, 1800, v1b, nullptr, nullptr);
  k_gemm<2><<<446 * 4,  256, 0, stream>>>(t2, u2c, 57024, 450,  57, 1824, 4,  t3, 512, 450, nullptr, nullptr, nullptr);
  k_gemm<3><<<446 * 8,  256, 0, stream>>>(t3, v2c, 57024, 900,  16, 512,  8,  nullptr, 0, 900, v2b, x, outF);
}

// Round 2
// 1495.616 us; speedup vs baseline: 1.0765x; 1.0765x over previous
//
#include <hip/hip_runtime.h>

// Block_21380347200224: LN1 -> 3D spectral filter (9x11x9, rfft last axis) -> LN2 ->
// low-rank MLP (900->450->1800 gelu ->450->900) -> +x residual.
// B=64, N=891, C=900, tokens M=57024.
//
// R2 pipeline:
//  k_cvt x4 + k_bias1 : weights -> bf16 (K-padded, gamma2/beta2 folded into GEMM1)
//  k_stats1    : LN1 mean/rstd per token (wave per token)
//  k_spectral  : block = (b, 16-chan chunk); full 3D filter in LDS:
//                d-rfft(9->5) -> 11pt w-DFT -> 9pt h-DFT * W * h-iDFT -> w-iDFT -> d-irfft
//                reads x once (205MB), writes y once (205MB)  [was 2.14GB over 5 kernels]
//  k_ln2       : LN2 -> ynorm bf16 (K-pad 928) in d_out
//  k_gemm<0..3>: bf16 MFMA GEMMs (128x128 tile, global_load_lds w=16)
//                gelu epilogue now tanh-form (exp+rcp), was erff (VALU-bound, 52% VALUBusy)
//
// ws: [0,205.3M) y fp32, reused as t2 (57024x1824 bf16, 208.0M)
//     [228.1M, 286.5M) t3 ; then bf16 weights + bias1r
// d_out scratch: ynorm [0,105.8M), t1 [105.8M,164.2M), stats [164.2M, +456K) — all dead
// before GEMM4 writes the final fp32 output over d_out.

typedef unsigned short u16;
typedef __bf16 bf16x8 __attribute__((ext_vector_type(8)));
typedef float f32x4 __attribute__((ext_vector_type(4)));

#define LN_EPS 1e-5f
#define CH 16   // channels per spectral block: LDS = 2*5*99*16*4 = 63360 B (<64KB static cap)

// ---------------- twiddle tables (folded to immediates after unroll) ----------------
constexpr float KC9[9] = {
  1.0f, 0.766044443118978f, 0.17364817766693041f, -0.4999999999999998f,
  -0.9396926207859083f, -0.9396926207859084f, -0.5000000000000004f,
  0.17364817766692997f, 0.7660444431189778f };
constexpr float KS9[9] = {
  0.0f, 0.6427876096865393f, 0.984807753012208f, 0.8660254037844387f,
  0.3420201433256689f, -0.34202014332566866f, -0.8660254037844385f,
  -0.9848077530122081f, -0.6427876096865396f };
constexpr float KC11[11] = {
  1.0f, 0.8412535328311812f, 0.41541501300188644f, -0.14231483827328512f,
  -0.654860733945285f, -0.9594929736144974f, -0.9594929736144974f,
  -0.6548607339452852f, -0.14231483827328543f, 0.4154150130018863f,
  0.8412535328311811f };
constexpr float KS11[11] = {
  0.0f, 0.5406408174555976f, 0.9096319953545183f, 0.9898214418809327f,
  0.7557495743542583f, 0.2817325568414297f, -0.2817325568414296f,
  -0.7557495743542582f, -0.9898214418809327f, -0.9096319953545184f,
  -0.5406408174555979f };

__device__ __forceinline__ u16 f2bf(float f) {           // RNE float->bf16
  unsigned int u = __float_as_uint(f);
  return (u16)((u + 0x7fffu + ((u >> 16) & 1u)) >> 16);
}
// tanh-form gelu: max |dev| from exact erf-gelu ~3e-4 (threshold 0.131). ~8 VALU ops.
__device__ __forceinline__ float gelu_f(float v) {
  float t = 0.7978845608028654f * v * (1.f + 0.044715f * v * v);
  float e = __expf(2.f * t);                       // v_exp_f32; inf/0 at extremes -> th -> +-1
  float th = 1.f - 2.f * __builtin_amdgcn_rcpf(e + 1.f);
  return 0.5f * v * (1.f + th);
}

// ---------------- weight conversion ----------------
__global__ __launch_bounds__(256) void k_cvt(const float* __restrict__ s, u16* __restrict__ d,
                                             int rows, int sc, int dc,
                                             const float* __restrict__ gamma) {
  int i = blockIdx.x * 256 + threadIdx.x;
  if (i >= rows * dc) return;
  int r = i / dc, c = i % dc;
  u16 o = 0;
  if (c < sc) {
    float v = s[(size_t)r * sc + c];
    if (gamma) v *= gamma[c];
    o = f2bf(v);
  }
  d[i] = o;
}

__global__ __launch_bounds__(256) void k_bias1(const float* __restrict__ u1w,
                                               const float* __restrict__ b2,
                                               float* __restrict__ out) {
  int r = blockIdx.x * 256 + threadIdx.x;
  if (r < 450) {
    float s = 0.f;
    for (int c = 0; c < 900; c++) s += u1w[r * 900 + c] * b2[c];
    out[r] = s;  // beta2 folded through u1
  }
}

// ---------------- LN1 stats: wave per token ----------------
__global__ __launch_bounds__(256) void k_stats1(const float* __restrict__ x,
                                                float2* __restrict__ stats) {
  int tok = blockIdx.x * 4 + (threadIdx.x >> 6);
  int l = threadIdx.x & 63;
  const float* row = x + (size_t)tok * 900;
  float s1 = 0.f, s2 = 0.f;
#pragma unroll
  for (int j = 0; j < 15; j++) {
    int c = l + j * 64;
    if (c < 900) { float a = row[c]; s1 += a; s2 += a * a; }
  }
#pragma unroll
  for (int off = 32; off; off >>= 1) { s1 += __shfl_xor(s1, off, 64); s2 += __shfl_xor(s2, off, 64); }
  if (l == 0) {
    float m = s1 * (1.f / 900.f);
    float var = s2 * (1.f / 900.f) - m * m;
    stats[tok] = make_float2(m, rsqrtf(var + LN_EPS));
  }
}

// ---------------- fused 3D spectral filter ----------------
// block = (b, cc); owns channels [cc*16, cc*16+16) across the whole 9x11x9 grid.
__global__ __launch_bounds__(256) void k_spectral(const float* __restrict__ x,
                                                  const float2* __restrict__ stats,
                                                  const float* __restrict__ g1,
                                                  const float* __restrict__ b1,
                                                  const float* __restrict__ cw,
                                                  float* __restrict__ y) {
  __shared__ float sre[5 * 99 * CH];
  __shared__ float sim[5 * 99 * CH];
  int b = blockIdx.x / 57, cc = blockIdx.x % 57;
  int c0 = cc * CH;
  int t = threadIdx.x;
  const float* xb = x + (size_t)b * 801900;
  const float2* st = stats + (size_t)b * 891;

  // pass 1: LN1 + d-rfft (9 -> 5)
  for (int col = t; col < 99 * CH; col += 256) {
    int pos = col / CH, c = col % CH;
    int cg = c0 + c; bool ok = cg < 900;
    float g = ok ? g1[cg] : 0.f, be = ok ? b1[cg] : 0.f;
    float yv[9];
#pragma unroll
    for (int d = 0; d < 9; d++) {
      float a = ok ? xb[(size_t)(pos * 9 + d) * 900 + cg] : 0.f;
      float2 s = st[pos * 9 + d];
      yv[d] = (a - s.x) * s.y * g + be;
    }
#pragma unroll
    for (int kd = 0; kd < 5; kd++) {
      float re = 0.f, im = 0.f;
#pragma unroll
      for (int d = 0; d < 9; d++) { int j = (kd * d) % 9; re += yv[d] * KC9[j]; im -= yv[d] * KS9[j]; }
      sre[(kd * 99 + pos) * CH + c] = re;
      sim[(kd * 99 + pos) * CH + c] = im;
    }
  }
  __syncthreads();

  // pass 2: forward 11-pt DFT over w (in-place per column)
  for (int col = t; col < 5 * 9 * CH; col += 256) {
    int kd = col / (9 * CH), r = col % (9 * CH), h = r / CH, c = r % CH;
    int base = (kd * 99 + h * 11) * CH + c;
    float xr[11], xi[11];
#pragma unroll
    for (int w = 0; w < 11; w++) { xr[w] = sre[base + w * CH]; xi[w] = sim[base + w * CH]; }
#pragma unroll
    for (int k = 0; k < 11; k++) {
      float yr = 0.f, yi = 0.f;
#pragma unroll
      for (int w = 0; w < 11; w++) {
        int j = (k * w) % 11; float cf = KC11[j], sf = KS11[j];
        yr += xr[w] * cf + xi[w] * sf;
        yi += xi[w] * cf - xr[w] * sf;
      }
      sre[base + k * CH] = yr; sim[base + k * CH] = yi;
    }
  }
  __syncthreads();

  // pass 3: 9-pt h-DFT * weight * 9-pt h-iDFT (in-place per column)
  for (int col = t; col < 5 * 11 * CH; col += 256) {
    int kd = col / (11 * CH), r = col % (11 * CH), kw = r / CH, c = r % CH;
    int cg = c0 + c;
    int base = (kd * 99 + kw) * CH + c;            // + h*11*CH
    float xr[9], xi[9];
#pragma unroll
    for (int h = 0; h < 9; h++) { xr[h] = sre[base + h * 11 * CH]; xi[h] = sim[base + h * 11 * CH]; }
    float zr[9], zi[9];
#pragma unroll
    for (int k = 0; k < 9; k++) {
      float yr = 0.f, yi = 0.f;
#pragma unroll
      for (int h = 0; h < 9; h++) {
        int j = (k * h) % 9; float cf = KC9[j], sf = KS9[j];
        yr += xr[h] * cf + xi[h] * sf;
        yi += xi[h] * cf - xr[h] * sf;
      }
      float wr = 0.f, wi = 0.f;
      if (cg < 900) {
        size_t widx = ((size_t)((k * 11 + kw) * 5 + kd) * 900 + cg) * 2;  // cw (kh,kw,kd,c,2)
        wr = cw[widx]; wi = cw[widx + 1];
      }
      zr[k] = yr * wr - yi * wi;
      zi[k] = yr * wi + yi * wr;
    }
#pragma unroll
    for (int h = 0; h < 9; h++) {
      float orr = 0.f, oi = 0.f;
#pragma unroll
      for (int k = 0; k < 9; k++) {
        int j = (k * h) % 9; float cf = KC9[j], sf = KS9[j];
        orr += zr[k] * cf - zi[k] * sf;
        oi  += zi[k] * cf + zr[k] * sf;
      }
      sre[base + h * 11 * CH] = orr; sim[base + h * 11 * CH] = oi;
    }
  }
  __syncthreads();

  // pass 4: inverse 11-pt DFT over w
  for (int col = t; col < 5 * 9 * CH; col += 256) {
    int kd = col / (9 * CH), r = col % (9 * CH), h = r / CH, c = r % CH;
    int base = (kd * 99 + h * 11) * CH + c;
    float xr[11], xi[11];
#pragma unroll
    for (int w = 0; w < 11; w++) { xr[w] = sre[base + w * CH]; xi[w] = sim[base + w * CH]; }
#pragma unroll
    for (int k = 0; k < 11; k++) {
      float yr = 0.f, yi = 0.f;
#pragma unroll
      for (int w = 0; w < 11; w++) {
        int j = (k * w) % 11; float cf = KC11[j], sf = KS11[j];
        yr += xr[w] * cf - xi[w] * sf;
        yi += xi[w] * cf + xr[w] * sf;
      }
      sre[base + k * CH] = yr; sim[base + k * CH] = yi;
    }
  }
  __syncthreads();

  // pass 5: d-irfft (5 -> 9), ortho scale, write y
  for (int col = t; col < 99 * CH; col += 256) {
    int pos = col / CH, c = col % CH;
    int cg = c0 + c;
    if (cg >= 900) continue;
    float Xr[5], Xi[5];
#pragma unroll
    for (int k = 0; k < 5; k++) { Xr[k] = sre[(k * 99 + pos) * CH + c]; Xi[k] = sim[(k * 99 + pos) * CH + c]; }
#pragma unroll
    for (int d = 0; d < 9; d++) {
      float acc = Xr[0];
#pragma unroll
      for (int k = 1; k < 5; k++) { int j = (k * d) % 9; acc += 2.f * (Xr[k] * KC9[j] - Xi[k] * KS9[j]); }
      y[((size_t)b * 891 + pos * 9 + d) * 900 + cg] = acc * (1.f / 891.f);
    }
  }
}

// ---------------- LN2 + bf16 emit: wave per token ----------------
__global__ __launch_bounds__(256) void k_ln2(const float* __restrict__ y, u16* __restrict__ yn) {
  int tok = blockIdx.x * 4 + (threadIdx.x >> 6);
  int l = threadIdx.x & 63;
  const float* row = y + (size_t)tok * 900;
  float v[15];
  float s1 = 0.f, s2 = 0.f;
#pragma unroll
  for (int j = 0; j < 15; j++) {
    int c = l + j * 64;
    float a = (c < 900) ? row[c] : 0.f;
    v[j] = a; s1 += a; s2 += a * a;
  }
#pragma unroll
  for (int off = 32; off; off >>= 1) { s1 += __shfl_xor(s1, off, 64); s2 += __shfl_xor(s2, off, 64); }
  float m = s1 * (1.f / 900.f);
  float var = s2 * (1.f / 900.f) - m * m;
  float rs = rsqrtf(var + LN_EPS);
  u16* orow = yn + (size_t)tok * 928;
#pragma unroll
  for (int j = 0; j < 15; j++) {
    int c = l + j * 64;
    if (c < 900) orow[c] = f2bf((v[j] - m) * rs);    // gamma2/beta2 folded into GEMM1
    else if (c < 928) orow[c] = 0;                   // K padding
  }
}

// ---------------- bf16 MFMA GEMM, C = A(MxK) . B(NxK)^T, m97-style ----------------
typedef __attribute__((address_space(1))) void gvoid;
typedef __attribute__((address_space(3))) void svoid;

__device__ __forceinline__ void stage16(const u16* g, u16* lbase, int lane) {
#if __has_builtin(__builtin_amdgcn_global_load_lds)
  __builtin_amdgcn_global_load_lds((gvoid*)(void*)g, (svoid*)lbase, 16, 0, 0);
#else
  *(uint4*)(lbase + lane * 8) = *(const uint4*)g;
#endif
}

// EPI: 0 = bf16 store + bias (G1)   1 = bf16 store gelu(.+bias) (G2)
//      2 = bf16 store plain (G3)    3 = fp32 out = . + bias + x (G4)
template <int EPI>
__global__ __launch_bounds__(256, 2) void k_gemm(
    const u16* __restrict__ A, const u16* __restrict__ B,
    int M, int N, int Kt, int ldk, int NT,
    u16* __restrict__ Ob, int ldo, int Nstore,
    const float* __restrict__ bias,
    const float* __restrict__ Xres, float* __restrict__ Of) {
  __shared__ u16 As[128 * 32];
  __shared__ u16 Bs[128 * 32];
  int t = threadIdx.x, w = t >> 6, l = t & 63;
  int mt = blockIdx.x / NT, nt = blockIdx.x % NT;
  int m0 = mt * 128, n0 = nt * 128;
  int arow = (w << 4) + (l >> 2);
  int koff = (l & 3) * 8;
  int wm = (w >> 1) << 6, wn = (w & 1) << 6;
  int fr = l & 15, fq = l >> 4;

  f32x4 acc[4][4];
  f32x4 zero = {0.f, 0.f, 0.f, 0.f};
#pragma unroll
  for (int i = 0; i < 4; i++)
#pragma unroll
    for (int j = 0; j < 4; j++) acc[i][j] = zero;

  for (int kt = 0; kt < Kt; ++kt) {
    int k0 = kt * 32;
#pragma unroll
    for (int j = 0; j < 2; j++) {
      int r = (j << 6) + arow;
      int gm = m0 + r; gm = gm < M ? gm : M - 1;
      stage16(A + (size_t)gm * ldk + (k0 + koff), &As[((j << 6) + (w << 4)) * 32], l);
      int gn = n0 + r; gn = gn < N ? gn : N - 1;
      stage16(B + (size_t)gn * ldk + (k0 + koff), &Bs[((j << 6) + (w << 4)) * 32], l);
    }
    __syncthreads();
    bf16x8 af[4], bfr[4];
#pragma unroll
    for (int i = 0; i < 4; i++) af[i] = *(const bf16x8*)&As[(wm + (i << 4) + fr) * 32 + fq * 8];
#pragma unroll
    for (int i = 0; i < 4; i++) bfr[i] = *(const bf16x8*)&Bs[(wn + (i << 4) + fr) * 32 + fq * 8];
#pragma unroll
    for (int i = 0; i < 4; i++)
#pragma unroll
      for (int j = 0; j < 4; j++)
        acc[i][j] = __builtin_amdgcn_mfma_f32_16x16x32_bf16(af[i], bfr[j], acc[i][j], 0, 0, 0);
    __syncthreads();
  }

#pragma unroll
  for (int j = 0; j < 4; j++) {
    int gn = n0 + wn + (j << 4) + fr;
    float bv = 0.f;
    if (EPI != 2) bv = (gn < Nstore) ? bias[gn] : 0.f;
#pragma unroll
    for (int i = 0; i < 4; i++) {
#pragma unroll
      for (int r = 0; r < 4; r++) {
        int gm = m0 + wm + (i << 4) + (fq << 2) + r;
        if (gm < M) {
          float val = acc[i][j][r] + bv;
          if (EPI == 1) val = gelu_f(val);
          if (EPI == 3) {
            if (gn < Nstore) Of[(size_t)gm * Nstore + gn] = val + Xres[(size_t)gm * Nstore + gn];
          } else {
            if (gn < ldo) Ob[(size_t)gm * ldo + gn] = (gn < Nstore) ? f2bf(val) : (u16)0;
          }
        }
      }
    }
  }
}

// ---------------- launch ----------------
extern "C" void kernel_launch(void* const* d_in, const int* in_sizes, int n_in,
                              void* d_out, int out_size, void* d_ws, size_t ws_size,
                              hipStream_t stream) {
  const float* x   = (const float*)d_in[0];
  const float* cw  = (const float*)d_in[1];
  const float* g1  = (const float*)d_in[2];
  const float* b1  = (const float*)d_in[3];
  const float* g2  = (const float*)d_in[4];
  const float* b2  = (const float*)d_in[5];
  const float* u1w = (const float*)d_in[6];
  const float* v1w = (const float*)d_in[7];
  const float* v1b = (const float*)d_in[8];
  const float* u2w = (const float*)d_in[9];
  const float* v2w = (const float*)d_in[10];
  const float* v2b = (const float*)d_in[11];

  char* ws = (char*)d_ws;
  float* y   = (float*)ws;                                   // 205,286,400 B
  u16*   t2  = (u16*)ws;                                     // reuse: 57024*1824*2 = 208,023,552 B
  u16*   t3  = (u16*)(ws + 228096000);                       // 58,392,576 B
  u16*   u1g = (u16*)(ws + 286488576);                       // 450*928*2
  u16*   v1c = (u16*)(ws + 287323776);                       // 1800*512*2
  u16*   u2c = (u16*)(ws + 289166976);                       // 450*1824*2
  u16*   v2c = (u16*)(ws + 290808576);                       // 900*512*2
  float* b1r = (float*)(ws + 291730176);                     // 450*4

  u16*    yn    = (u16*)d_out;                               // 57024*928*2 = 105,836,544 B
  u16*    t1    = (u16*)((char*)d_out + 105836544);          // 57024*512*2 = 58,392,576 B
  float2* stats = (float2*)((char*)d_out + 164229120);       // 57024*8 = 456,192 B
  float*  outF  = (float*)d_out;

  // weight prep (tiny)
  k_cvt<<<1632, 256, 0, stream>>>(u1w, u1g, 450, 900, 928, g2);
  k_cvt<<<3600, 256, 0, stream>>>(v1w, v1c, 1800, 450, 512, nullptr);
  k_cvt<<<3207, 256, 0, stream>>>(u2w, u2c, 450, 1800, 1824, nullptr);
  k_cvt<<<1800, 256, 0, stream>>>(v2w, v2c, 900, 450, 512, nullptr);
  k_bias1<<<2, 256, 0, stream>>>(u1w, b2, b1r);

  // spectral filter (fused)
  k_stats1<<<14256, 256, 0, stream>>>(x, stats);
  k_spectral<<<64 * 57, 256, 0, stream>>>(x, stats, g1, b1, cw, y);
  k_ln2<<<14256, 256, 0, stream>>>(y, yn);

  // MLP GEMMs: M=57024 (446 tiles of 128)
  k_gemm<0><<<446 * 4,  256, 0, stream>>>(yn, u1g, 57024, 450,  29, 928,  4,  t1, 512, 450, b1r, nullptr, nullptr);
  k_gemm<1><<<446 * 15, 256, 0, stream>>>(t1, v1c, 57024, 1800, 16, 512,  15, t2, 1824, 1800, v1b, nullptr, nullptr);
  k_gemm<2><<<446 * 4,  256, 0, stream>>>(t2, u2c, 57024, 450,  57, 1824, 4,  t3, 512, 450, nullptr, nullptr, nullptr);
  k_gemm<3><<<446 * 8,  256, 0, stream>>>(t3, v2c, 57024, 900,  16, 512,  8,  nullptr, 0, 900, v2b, x, outF);
}

// Round 3
// 1491.291 us; speedup vs baseline: 1.0797x; 1.0029x over previous
//
#include <hip/hip_runtime.h>

// Block_21380347200224: LN1 -> 3D spectral filter (9x11x9, rfft last axis) -> LN2 ->
// low-rank MLP (900->450->1800 gelu ->450->900) -> +x residual.
// B=64, N=891, C=900, tokens M=57024.
//
// R3: GEMM K-loop restructured as 2-stage software pipeline (the R2 profile showed
// MfmaUtil 8.5% / VALUBusy 7.9% — barrier-drain stall-bound, not BW or compute).
//  - double-buffered LDS (2x16KB), prologue stages tiles 0,1
//  - per iter: `s_waitcnt vmcnt(4)` + raw `s_barrier` (inline asm, memory clobber)
//    so the NEXT tile's 4 global_load_lds stay in flight across the barrier
//  - compute, barrier, stage tile k+2 into the just-consumed buffer
// Rest of pipeline unchanged from R2 (fused spectral filter, tanh-gelu epilogue).

typedef unsigned short u16;
typedef __bf16 bf16x8 __attribute__((ext_vector_type(8)));
typedef float f32x4 __attribute__((ext_vector_type(4)));

#define LN_EPS 1e-5f
#define CH 16   // channels per spectral block: LDS = 2*5*99*16*4 = 63360 B

// ---------------- twiddle tables (folded to immediates after unroll) ----------------
constexpr float KC9[9] = {
  1.0f, 0.766044443118978f, 0.17364817766693041f, -0.4999999999999998f,
  -0.9396926207859083f, -0.9396926207859084f, -0.5000000000000004f,
  0.17364817766692997f, 0.7660444431189778f };
constexpr float KS9[9] = {
  0.0f, 0.6427876096865393f, 0.984807753012208f, 0.8660254037844387f,
  0.3420201433256689f, -0.34202014332566866f, -0.8660254037844385f,
  -0.9848077530122081f, -0.6427876096865396f };
constexpr float KC11[11] = {
  1.0f, 0.8412535328311812f, 0.41541501300188644f, -0.14231483827328512f,
  -0.654860733945285f, -0.9594929736144974f, -0.9594929736144974f,
  -0.6548607339452852f, -0.14231483827328543f, 0.4154150130018863f,
  0.8412535328311811f };
constexpr float KS11[11] = {
  0.0f, 0.5406408174555976f, 0.9096319953545183f, 0.9898214418809327f,
  0.7557495743542583f, 0.2817325568414297f, -0.2817325568414296f,
  -0.7557495743542582f, -0.9898214418809327f, -0.9096319953545184f,
  -0.5406408174555979f };

__device__ __forceinline__ u16 f2bf(float f) {           // RNE float->bf16
  unsigned int u = __float_as_uint(f);
  return (u16)((u + 0x7fffu + ((u >> 16) & 1u)) >> 16);
}
// tanh-form gelu: max |dev| from exact erf-gelu ~3e-4 (threshold 0.131). ~8 VALU ops.
__device__ __forceinline__ float gelu_f(float v) {
  float t = 0.7978845608028654f * v * (1.f + 0.044715f * v * v);
  float e = __expf(2.f * t);
  float th = 1.f - 2.f * __builtin_amdgcn_rcpf(e + 1.f);
  return 0.5f * v * (1.f + th);
}

// ---------------- weight conversion ----------------
__global__ __launch_bounds__(256) void k_cvt(const float* __restrict__ s, u16* __restrict__ d,
                                             int rows, int sc, int dc,
                                             const float* __restrict__ gamma) {
  int i = blockIdx.x * 256 + threadIdx.x;
  if (i >= rows * dc) return;
  int r = i / dc, c = i % dc;
  u16 o = 0;
  if (c < sc) {
    float v = s[(size_t)r * sc + c];
    if (gamma) v *= gamma[c];
    o = f2bf(v);
  }
  d[i] = o;
}

__global__ __launch_bounds__(256) void k_bias1(const float* __restrict__ u1w,
                                               const float* __restrict__ b2,
                                               float* __restrict__ out) {
  int r = blockIdx.x * 256 + threadIdx.x;
  if (r < 450) {
    float s = 0.f;
    for (int c = 0; c < 900; c++) s += u1w[r * 900 + c] * b2[c];
    out[r] = s;  // beta2 folded through u1
  }
}

// ---------------- LN1 stats: wave per token ----------------
__global__ __launch_bounds__(256) void k_stats1(const float* __restrict__ x,
                                                float2* __restrict__ stats) {
  int tok = blockIdx.x * 4 + (threadIdx.x >> 6);
  int l = threadIdx.x & 63;
  const float* row = x + (size_t)tok * 900;
  float s1 = 0.f, s2 = 0.f;
#pragma unroll
  for (int j = 0; j < 15; j++) {
    int c = l + j * 64;
    if (c < 900) { float a = row[c]; s1 += a; s2 += a * a; }
  }
#pragma unroll
  for (int off = 32; off; off >>= 1) { s1 += __shfl_xor(s1, off, 64); s2 += __shfl_xor(s2, off, 64); }
  if (l == 0) {
    float m = s1 * (1.f / 900.f);
    float var = s2 * (1.f / 900.f) - m * m;
    stats[tok] = make_float2(m, rsqrtf(var + LN_EPS));
  }
}

// ---------------- fused 3D spectral filter ----------------
__global__ __launch_bounds__(256) void k_spectral(const float* __restrict__ x,
                                                  const float2* __restrict__ stats,
                                                  const float* __restrict__ g1,
                                                  const float* __restrict__ b1,
                                                  const float* __restrict__ cw,
                                                  float* __restrict__ y) {
  __shared__ float sre[5 * 99 * CH];
  __shared__ float sim[5 * 99 * CH];
  int b = blockIdx.x / 57, cc = blockIdx.x % 57;
  int c0 = cc * CH;
  int t = threadIdx.x;
  const float* xb = x + (size_t)b * 801900;
  const float2* st = stats + (size_t)b * 891;

  // pass 1: LN1 + d-rfft (9 -> 5)
  for (int col = t; col < 99 * CH; col += 256) {
    int pos = col / CH, c = col % CH;
    int cg = c0 + c; bool ok = cg < 900;
    float g = ok ? g1[cg] : 0.f, be = ok ? b1[cg] : 0.f;
    float yv[9];
#pragma unroll
    for (int d = 0; d < 9; d++) {
      float a = ok ? xb[(size_t)(pos * 9 + d) * 900 + cg] : 0.f;
      float2 s = st[pos * 9 + d];
      yv[d] = (a - s.x) * s.y * g + be;
    }
#pragma unroll
    for (int kd = 0; kd < 5; kd++) {
      float re = 0.f, im = 0.f;
#pragma unroll
      for (int d = 0; d < 9; d++) { int j = (kd * d) % 9; re += yv[d] * KC9[j]; im -= yv[d] * KS9[j]; }
      sre[(kd * 99 + pos) * CH + c] = re;
      sim[(kd * 99 + pos) * CH + c] = im;
    }
  }
  __syncthreads();

  // pass 2: forward 11-pt DFT over w
  for (int col = t; col < 5 * 9 * CH; col += 256) {
    int kd = col / (9 * CH), r = col % (9 * CH), h = r / CH, c = r % CH;
    int base = (kd * 99 + h * 11) * CH + c;
    float xr[11], xi[11];
#pragma unroll
    for (int w = 0; w < 11; w++) { xr[w] = sre[base + w * CH]; xi[w] = sim[base + w * CH]; }
#pragma unroll
    for (int k = 0; k < 11; k++) {
      float yr = 0.f, yi = 0.f;
#pragma unroll
      for (int w = 0; w < 11; w++) {
        int j = (k * w) % 11; float cf = KC11[j], sf = KS11[j];
        yr += xr[w] * cf + xi[w] * sf;
        yi += xi[w] * cf - xr[w] * sf;
      }
      sre[base + k * CH] = yr; sim[base + k * CH] = yi;
    }
  }
  __syncthreads();

  // pass 3: 9-pt h-DFT * weight * 9-pt h-iDFT
  for (int col = t; col < 5 * 11 * CH; col += 256) {
    int kd = col / (11 * CH), r = col % (11 * CH), kw = r / CH, c = r % CH;
    int cg = c0 + c;
    int base = (kd * 99 + kw) * CH + c;
    float xr[9], xi[9];
#pragma unroll
    for (int h = 0; h < 9; h++) { xr[h] = sre[base + h * 11 * CH]; xi[h] = sim[base + h * 11 * CH]; }
    float zr[9], zi[9];
#pragma unroll
    for (int k = 0; k < 9; k++) {
      float yr = 0.f, yi = 0.f;
#pragma unroll
      for (int h = 0; h < 9; h++) {
        int j = (k * h) % 9; float cf = KC9[j], sf = KS9[j];
        yr += xr[h] * cf + xi[h] * sf;
        yi += xi[h] * cf - xr[h] * sf;
      }
      float wr = 0.f, wi = 0.f;
      if (cg < 900) {
        size_t widx = ((size_t)((k * 11 + kw) * 5 + kd) * 900 + cg) * 2;
        wr = cw[widx]; wi = cw[widx + 1];
      }
      zr[k] = yr * wr - yi * wi;
      zi[k] = yr * wi + yi * wr;
    }
#pragma unroll
    for (int h = 0; h < 9; h++) {
      float orr = 0.f, oi = 0.f;
#pragma unroll
      for (int k = 0; k < 9; k++) {
        int j = (k * h) % 9; float cf = KC9[j], sf = KS9[j];
        orr += zr[k] * cf - zi[k] * sf;
        oi  += zi[k] * cf + zr[k] * sf;
      }
      sre[base + h * 11 * CH] = orr; sim[base + h * 11 * CH] = oi;
    }
  }
  __syncthreads();

  // pass 4: inverse 11-pt DFT over w
  for (int col = t; col < 5 * 9 * CH; col += 256) {
    int kd = col / (9 * CH), r = col % (9 * CH), h = r / CH, c = r % CH;
    int base = (kd * 99 + h * 11) * CH + c;
    float xr[11], xi[11];
#pragma unroll
    for (int w = 0; w < 11; w++) { xr[w] = sre[base + w * CH]; xi[w] = sim[base + w * CH]; }
#pragma unroll
    for (int k = 0; k < 11; k++) {
      float yr = 0.f, yi = 0.f;
#pragma unroll
      for (int w = 0; w < 11; w++) {
        int j = (k * w) % 11; float cf = KC11[j], sf = KS11[j];
        yr += xr[w] * cf - xi[w] * sf;
        yi += xi[w] * cf + xr[w] * sf;
      }
      sre[base + k * CH] = yr; sim[base + k * CH] = yi;
    }
  }
  __syncthreads();

  // pass 5: d-irfft (5 -> 9), ortho scale, write y
  for (int col = t; col < 99 * CH; col += 256) {
    int pos = col / CH, c = col % CH;
    int cg = c0 + c;
    if (cg >= 900) continue;
    float Xr[5], Xi[5];
#pragma unroll
    for (int k = 0; k < 5; k++) { Xr[k] = sre[(k * 99 + pos) * CH + c]; Xi[k] = sim[(k * 99 + pos) * CH + c]; }
#pragma unroll
    for (int d = 0; d < 9; d++) {
      float acc = Xr[0];
#pragma unroll
      for (int k = 1; k < 5; k++) { int j = (k * d) % 9; acc += 2.f * (Xr[k] * KC9[j] - Xi[k] * KS9[j]); }
      y[((size_t)b * 891 + pos * 9 + d) * 900 + cg] = acc * (1.f / 891.f);
    }
  }
}

// ---------------- LN2 + bf16 emit: wave per token ----------------
__global__ __launch_bounds__(256) void k_ln2(const float* __restrict__ y, u16* __restrict__ yn) {
  int tok = blockIdx.x * 4 + (threadIdx.x >> 6);
  int l = threadIdx.x & 63;
  const float* row = y + (size_t)tok * 900;
  float v[15];
  float s1 = 0.f, s2 = 0.f;
#pragma unroll
  for (int j = 0; j < 15; j++) {
    int c = l + j * 64;
    float a = (c < 900) ? row[c] : 0.f;
    v[j] = a; s1 += a; s2 += a * a;
  }
#pragma unroll
  for (int off = 32; off; off >>= 1) { s1 += __shfl_xor(s1, off, 64); s2 += __shfl_xor(s2, off, 64); }
  float m = s1 * (1.f / 900.f);
  float var = s2 * (1.f / 900.f) - m * m;
  float rs = rsqrtf(var + LN_EPS);
  u16* orow = yn + (size_t)tok * 928;
#pragma unroll
  for (int j = 0; j < 15; j++) {
    int c = l + j * 64;
    if (c < 900) orow[c] = f2bf((v[j] - m) * rs);
    else if (c < 928) orow[c] = 0;
  }
}

// ---------------- bf16 MFMA GEMM, C = A(MxK) . B(NxK)^T, 2-stage pipelined ----------------
typedef __attribute__((address_space(1))) void gvoid;
typedef __attribute__((address_space(3))) void svoid;

__device__ __forceinline__ void stage16(const u16* g, u16* lbase) {
  __builtin_amdgcn_global_load_lds((gvoid*)(void*)g, (svoid*)lbase, 16, 0, 0);
}

// stage one 128x32 A-tile + 128x32 B-tile: 4 global_load_lds per thread (A,B,A,B)
__device__ __forceinline__ void stage_tile(const u16* __restrict__ A, const u16* __restrict__ B,
                                           int m0, int n0, int M, int N, int ldk, int k0,
                                           u16* As, u16* Bs, int w, int l) {
  int arow = (w << 4) + (l >> 2);
  int koff = k0 + (l & 3) * 8;
#pragma unroll
  for (int j = 0; j < 2; j++) {
    int r = (j << 6) + arow;
    int gm = m0 + r; gm = gm < M ? gm : M - 1;
    stage16(A + (size_t)gm * ldk + koff, &As[((j << 6) + (w << 4)) * 32]);
    int gn = n0 + r; gn = gn < N ? gn : N - 1;
    stage16(B + (size_t)gn * ldk + koff, &Bs[((j << 6) + (w << 4)) * 32]);
  }
}

// EPI: 0 = bf16 store + bias (G1)   1 = bf16 store gelu(.+bias) (G2)
//      2 = bf16 store plain (G3)    3 = fp32 out = . + bias + x (G4)
template <int EPI>
__global__ __launch_bounds__(256, 2) void k_gemm(
    const u16* __restrict__ A, const u16* __restrict__ B,
    int M, int N, int Kt, int ldk, int NT,
    u16* __restrict__ Ob, int ldo, int Nstore,
    const float* __restrict__ bias,
    const float* __restrict__ Xres, float* __restrict__ Of) {
  __shared__ u16 As[2][128 * 32];
  __shared__ u16 Bs[2][128 * 32];
  int t = threadIdx.x, w = t >> 6, l = t & 63;
  int mt = blockIdx.x / NT, nt = blockIdx.x % NT;
  int m0 = mt * 128, n0 = nt * 128;
  int wm = (w >> 1) << 6, wn = (w & 1) << 6;
  int fr = l & 15, fq = l >> 4;

  f32x4 acc[4][4];
  f32x4 zero = {0.f, 0.f, 0.f, 0.f};
#pragma unroll
  for (int i = 0; i < 4; i++)
#pragma unroll
    for (int j = 0; j < 4; j++) acc[i][j] = zero;

  // prologue: tiles 0 and 1 in flight
  stage_tile(A, B, m0, n0, M, N, ldk, 0, As[0], Bs[0], w, l);
  if (Kt > 1) stage_tile(A, B, m0, n0, M, N, ldk, 32, As[1], Bs[1], w, l);

  for (int kt = 0; kt < Kt; ++kt) {
    // drain ONLY tile kt's 4 loads (tile kt+1's 4 stay in flight), then barrier.
    // Raw asm: __syncthreads() would force vmcnt(0) and kill the pipeline.
    if (kt + 1 < Kt) asm volatile("s_waitcnt vmcnt(4)\n\ts_barrier" ::: "memory");
    else             asm volatile("s_waitcnt vmcnt(0)\n\ts_barrier" ::: "memory");

    const u16* as = As[kt & 1];
    const u16* bs = Bs[kt & 1];
    bf16x8 af[4], bfr[4];
#pragma unroll
    for (int i = 0; i < 4; i++) af[i] = *(const bf16x8*)&as[(wm + (i << 4) + fr) * 32 + fq * 8];
#pragma unroll
    for (int i = 0; i < 4; i++) bfr[i] = *(const bf16x8*)&bs[(wn + (i << 4) + fr) * 32 + fq * 8];
#pragma unroll
    for (int i = 0; i < 4; i++)
#pragma unroll
      for (int j = 0; j < 4; j++)
        acc[i][j] = __builtin_amdgcn_mfma_f32_16x16x32_bf16(af[i], bfr[j], acc[i][j], 0, 0, 0);

    // all waves done reading buf[kt&1] before restaging into it
    asm volatile("s_barrier" ::: "memory");
    if (kt + 2 < Kt)
      stage_tile(A, B, m0, n0, M, N, ldk, (kt + 2) * 32, As[kt & 1], Bs[kt & 1], w, l);
  }

#pragma unroll
  for (int j = 0; j < 4; j++) {
    int gn = n0 + wn + (j << 4) + fr;
    float bv = 0.f;
    if (EPI != 2) bv = (gn < Nstore) ? bias[gn] : 0.f;
#pragma unroll
    for (int i = 0; i < 4; i++) {
#pragma unroll
      for (int r = 0; r < 4; r++) {
        int gm = m0 + wm + (i << 4) + (fq << 2) + r;
        if (gm < M) {
          float val = acc[i][j][r] + bv;
          if (EPI == 1) val = gelu_f(val);
          if (EPI == 3) {
            if (gn < Nstore) Of[(size_t)gm * Nstore + gn] = val + Xres[(size_t)gm * Nstore + gn];
          } else {
            if (gn < ldo) Ob[(size_t)gm * ldo + gn] = (gn < Nstore) ? f2bf(val) : (u16)0;
          }
        }
      }
    }
  }
}

// ---------------- launch ----------------
extern "C" void kernel_launch(void* const* d_in, const int* in_sizes, int n_in,
                              void* d_out, int out_size, void* d_ws, size_t ws_size,
                              hipStream_t stream) {
  const float* x   = (const float*)d_in[0];
  const float* cw  = (const float*)d_in[1];
  const float* g1  = (const float*)d_in[2];
  const float* b1  = (const float*)d_in[3];
  const float* g2  = (const float*)d_in[4];
  const float* b2  = (const float*)d_in[5];
  const float* u1w = (const float*)d_in[6];
  const float* v1w = (const float*)d_in[7];
  const float* v1b = (const float*)d_in[8];
  const float* u2w = (const float*)d_in[9];
  const float* v2w = (const float*)d_in[10];
  const float* v2b = (const float*)d_in[11];

  char* ws = (char*)d_ws;
  float* y   = (float*)ws;                                   // 205,286,400 B
  u16*   t2  = (u16*)ws;                                     // reuse: 57024*1824*2 = 208,023,552 B
  u16*   t3  = (u16*)(ws + 228096000);                       // 58,392,576 B
  u16*   u1g = (u16*)(ws + 286488576);                       // 450*928*2
  u16*   v1c = (u16*)(ws + 287323776);                       // 1800*512*2
  u16*   u2c = (u16*)(ws + 289166976);                       // 450*1824*2
  u16*   v2c = (u16*)(ws + 290808576);                       // 900*512*2
  float* b1r = (float*)(ws + 291730176);                     // 450*4

  u16*    yn    = (u16*)d_out;                               // 57024*928*2 = 105,836,544 B
  u16*    t1    = (u16*)((char*)d_out + 105836544);          // 57024*512*2 = 58,392,576 B
  float2* stats = (float2*)((char*)d_out + 164229120);       // 57024*8 = 456,192 B
  float*  outF  = (float*)d_out;

  // weight prep (tiny)
  k_cvt<<<1632, 256, 0, stream>>>(u1w, u1g, 450, 900, 928, g2);
  k_cvt<<<3600, 256, 0, stream>>>(v1w, v1c, 1800, 450, 512, nullptr);
  k_cvt<<<3207, 256, 0, stream>>>(u2w, u2c, 450, 1800, 1824, nullptr);
  k_cvt<<<1800, 256, 0, stream>>>(v2w, v2c, 900, 450, 512, nullptr);
  k_bias1<<<2, 256, 0, stream>>>(u1w, b2, b1r);

  // spectral filter (fused)
  k_stats1<<<14256, 256, 0, stream>>>(x, stats);
  k_spectral<<<64 * 57, 256, 0, stream>>>(x, stats, g1, b1, cw, y);
  k_ln2<<<14256, 256, 0, stream>>>(y, yn);

  // MLP GEMMs: M=57024 (446 tiles of 128)
  k_gemm<0><<<446 * 4,  256, 0, stream>>>(yn, u1g, 57024, 450,  29, 928,  4,  t1, 512, 450, b1r, nullptr, nullptr);
  k_gemm<1><<<446 * 15, 256, 0, stream>>>(t1, v1c, 57024, 1800, 16, 512,  15, t2, 1824, 1800, v1b, nullptr, nullptr);
  k_gemm<2><<<446 * 4,  256, 0, stream>>>(t2, u2c, 57024, 450,  57, 1824, 4,  t3, 512, 450, nullptr, nullptr, nullptr);
  k_gemm<3><<<446 * 8,  256, 0, stream>>>(t3, v2c, 57024, 900,  16, 512,  8,  nullptr, 0, 900, v2b, x, outF);
}